// Round 6
// baseline (1022.879 us; speedup 1.0000x reference)
//
#include <hip/hip_runtime.h>

#define NNODES 50000
#define NEDGES 800000
#define NCHUNK 196   // ceil(50000/256)

typedef __attribute__((ext_vector_type(8))) short short8;
typedef __attribute__((ext_vector_type(4))) float f32x4;

__device__ __forceinline__ float silu_f(float x) {
    return __fdividef(x, 1.0f + __expf(-x));
}
__device__ __forceinline__ unsigned bf16rne(float x) {
    unsigned u = __float_as_uint(x);
    return (u + 0x7FFFu + ((u >> 16) & 1u)) >> 16;
}
__device__ __forceinline__ float bf2f(unsigned short h) {
    return __uint_as_float(((unsigned)h) << 16);
}

// ---------------- h0/h1 (bf16 out) ----------------
__global__ __launch_bounds__(128) void node_prep_kernel(
    const float* __restrict__ nf, const float* __restrict__ w0,
    const float* __restrict__ w1, unsigned short* __restrict__ h0b,
    unsigned short* __restrict__ h1b)
{
    __shared__ float row[128];
    const int n = blockIdx.x;
    const int j = threadIdx.x;
    row[j] = nf[n * 128 + j];
    __syncthreads();
    const float l1 = 0.17677669529663687f; // 1/sqrt(32)
    if (j < 32) {
        float acc = 0.0f;
        #pragma unroll
        for (int u = 0; u < 32; ++u) acc += row[u] * w0[u * 32 + j];
        h0b[n * 32 + j] = (unsigned short)bf16rne(acc * l1);
    } else {
        const int i = j - 32;
        const int v = i / 3;
        const int m = i - 3 * v;
        float acc = 0.0f;
        #pragma unroll
        for (int u = 0; u < 32; ++u) acc += row[32 + u * 3 + m] * w1[u * 32 + v];
        h1b[n * 96 + i] = (unsigned short)bf16rne(acc * l1);
    }
}

// ---------------- self-connection scalar+gate
__global__ __launch_bounds__(256) void sc_scalar_kernel(
    const float* __restrict__ nf, const float* __restrict__ za,
    const float* __restrict__ wS, const float* __restrict__ wG,
    float* __restrict__ scs, float* __restrict__ scg)
{
    const int t = blockIdx.x * 256 + threadIdx.x;
    const int lane = t & 63;
    const int h = __builtin_amdgcn_readfirstlane((t >> 6) & 1);
    const int n = (t >> 7) * 64 + lane;
    if (n >= NNODES) return;
    const float* x0p = nf + n * 128;
    const float* zp  = za + n * 16;
    const float* bS0 = wS + h * 16;
    const float* bG0 = wG + h * 16;
    float accS[16], accG[16];
    #pragma unroll
    for (int w = 0; w < 16; ++w) { accS[w] = 0.0f; accG[w] = 0.0f; }
    for (int u = 0; u < 32; ++u) {
        const float xu = x0p[u];
        for (int v = 0; v < 16; ++v) {
            const float p = xu * zp[v];
            const float* bS = bS0 + (u * 16 + v) * 32;
            const float* bG = bG0 + (u * 16 + v) * 32;
            #pragma unroll
            for (int w = 0; w < 16; w += 4) {
                const float4 qs = *(const float4*)(bS + w);
                const float4 qg = *(const float4*)(bG + w);
                accS[w+0] += p * qs.x; accS[w+1] += p * qs.y;
                accS[w+2] += p * qs.z; accS[w+3] += p * qs.w;
                accG[w+0] += p * qg.x; accG[w+1] += p * qg.y;
                accG[w+2] += p * qg.z; accG[w+3] += p * qg.w;
            }
        }
    }
    const float scn = 0.04419417382415922f; // 1/sqrt(512)
    #pragma unroll
    for (int w = 0; w < 16; ++w) {
        scs[n * 32 + h * 16 + w] = accS[w] * scn;
        scg[n * 32 + h * 16 + w] = accG[w] * scn;
    }
}

// ---------------- self-connection vector
__global__ __launch_bounds__(256) void sc_vec_kernel(
    const float* __restrict__ nf, const float* __restrict__ za,
    const float* __restrict__ wV, float* __restrict__ scv)
{
    const int t = blockIdx.x * 256 + threadIdx.x;
    if (t >= NNODES * 3) return;
    const int n = t / 3;
    const int m = t - 3 * n;
    const float* x1p = nf + n * 128 + 32 + m;
    const float* zp  = za + n * 16;
    float acc[32];
    #pragma unroll
    for (int w = 0; w < 32; ++w) acc[w] = 0.0f;
    for (int u = 0; u < 32; ++u) {
        const float xu = x1p[u * 3];
        for (int v = 0; v < 16; ++v) {
            const float p = xu * zp[v];
            const float* bV = wV + (u * 16 + v) * 32;
            #pragma unroll
            for (int w = 0; w < 32; w += 4) {
                const float4 q = *(const float4*)(bV + w);
                acc[w+0] += p * q.x; acc[w+1] += p * q.y;
                acc[w+2] += p * q.z; acc[w+3] += p * q.w;
            }
        }
    }
    const float scn = 0.04419417382415922f;
    #pragma unroll
    for (int w = 0; w < 32; ++w) scv[n * 96 + w * 3 + m] = acc[w] * scn;
}

// ---------------- CSR build ----------------
__global__ __launch_bounds__(256) void hist_kernel(const int* __restrict__ edst,
                                                   int* __restrict__ cnt) {
    const int e = blockIdx.x * 256 + threadIdx.x;
    if (e < NEDGES) atomicAdd(&cnt[edst[e]], 1);
}

__global__ __launch_bounds__(256) void scan_a_kernel(const int* __restrict__ cnt,
                                                     int* __restrict__ bsum) {
    __shared__ int s[256];
    const int t = threadIdx.x;
    const int idx = blockIdx.x * 256 + t;
    s[t] = (idx < NNODES) ? cnt[idx] : 0;
    __syncthreads();
    for (int off = 128; off > 0; off >>= 1) {
        if (t < off) s[t] += s[t + off];
        __syncthreads();
    }
    if (t == 0) bsum[blockIdx.x] = s[0];
}

__global__ __launch_bounds__(256) void scan_b_kernel(const int* __restrict__ bsum,
                                                     int* __restrict__ boff) {
    __shared__ int s[256];
    const int t = threadIdx.x;
    const int v = (t < NCHUNK) ? bsum[t] : 0;
    s[t] = v;
    __syncthreads();
    for (int off = 1; off < 256; off <<= 1) {
        int x = (t >= off) ? s[t - off] : 0;
        __syncthreads();
        s[t] += x;
        __syncthreads();
    }
    if (t < NCHUNK) boff[t] = s[t] - v;   // exclusive
}

__global__ __launch_bounds__(256) void scan_c_kernel(const int* __restrict__ cnt,
                                                     const int* __restrict__ boff,
                                                     int* __restrict__ rowstart,
                                                     int* __restrict__ cur) {
    __shared__ int s[256];
    const int t = threadIdx.x;
    const int idx = blockIdx.x * 256 + t;
    const int v = (idx < NNODES) ? cnt[idx] : 0;
    s[t] = v;
    __syncthreads();
    for (int off = 1; off < 256; off <<= 1) {
        int x = (t >= off) ? s[t - off] : 0;
        __syncthreads();
        s[t] += x;
        __syncthreads();
    }
    if (idx < NNODES) {
        const int excl = s[t] - v + boff[blockIdx.x];
        rowstart[idx] = excl;
        cur[idx] = excl;
    }
}

__global__ __launch_bounds__(256) void fill_kernel(const int* __restrict__ edst,
                                                   int* __restrict__ cur,
                                                   int* __restrict__ eid) {
    const int e = blockIdx.x * 256 + threadIdx.x;
    if (e < NEDGES) {
        const int p = atomicAdd(&cur[edst[e]], 1);
        eid[p] = e;
    }
}

// ---------------- weight prep: bf16 + transpose + XOR swizzle into 32KB blob ----
// Layout (shorts): W0 at 0 (64 n-rows x 64), W1 at 4096, W2 at 8192 (128 x 64).
// Row n, k-block kb lives at n*64 + ((kb ^ (n&7))*8).
__global__ __launch_bounds__(256) void wprep_kernel(
    const float* __restrict__ fw0, const float* __restrict__ fw1,
    const float* __restrict__ fw2, unsigned short* __restrict__ wb)
{
    const int t = threadIdx.x;
    for (int s = t; s < 512; s += 256) {          // W0: fw0 is [8][64]
        const int n = s >> 3, kb = s & 7;
        uint4 v = {0u, 0u, 0u, 0u};
        if (kb == 0) {
            unsigned h[8];
            #pragma unroll
            for (int i = 0; i < 8; ++i) h[i] = bf16rne(fw0[i * 64 + n]);
            v.x = h[0] | (h[1] << 16); v.y = h[2] | (h[3] << 16);
            v.z = h[4] | (h[5] << 16); v.w = h[6] | (h[7] << 16);
        }
        *(uint4*)&wb[n * 64 + ((kb ^ (n & 7)) * 8)] = v;
    }
    for (int s = t; s < 512; s += 256) {          // W1: fw1 is [64][64]
        const int n = s >> 3, kb = s & 7;
        unsigned h[8];
        #pragma unroll
        for (int i = 0; i < 8; ++i) h[i] = bf16rne(fw1[(kb * 8 + i) * 64 + n]);
        uint4 v;
        v.x = h[0] | (h[1] << 16); v.y = h[2] | (h[3] << 16);
        v.z = h[4] | (h[5] << 16); v.w = h[6] | (h[7] << 16);
        *(uint4*)&wb[4096 + n * 64 + ((kb ^ (n & 7)) * 8)] = v;
    }
    for (int s = t; s < 1024; s += 256) {         // W2: fw2 is [64][128]
        const int n = s >> 3, kb = s & 7;
        unsigned h[8];
        #pragma unroll
        for (int i = 0; i < 8; ++i) h[i] = bf16rne(fw2[(kb * 8 + i) * 128 + n]);
        uint4 v;
        v.x = h[0] | (h[1] << 16); v.y = h[2] | (h[3] << 16);
        v.z = h[4] | (h[5] << 16); v.w = h[6] | (h[7] << 16);
        *(uint4*)&wb[8192 + n * 64 + ((kb ^ (n & 7)) * 8)] = v;
    }
}

// ---------------- FUSED: per-node edge MLP (MFMA) + tensor product + lin2 + out ----
// 512 threads = 2 node-contexts (half = t>>8) sharing one 32KB weight stage.
// Barrier trip count is uniform: chunks = ceil(max(degA,degB)/16).
__global__ __launch_bounds__(512, 2) void fused_gather_kernel(
    const float* __restrict__ eemb, const float* __restrict__ esh,
    const int* __restrict__ esrc, const int* __restrict__ eid,
    const int* __restrict__ rowstart, const int* __restrict__ cnt,
    const unsigned short* __restrict__ wblob,
    const unsigned short* __restrict__ h0b, const unsigned short* __restrict__ h1b,
    const float* __restrict__ scs, const float* __restrict__ scg,
    const float* __restrict__ scv,
    const float* __restrict__ l2w0, const float* __restrict__ l2w1,
    float* __restrict__ out)
{
    __shared__ uint4 WB4[2048];                       // 32 KB weights
    __shared__ __attribute__((aligned(16))) short XA[2][3][1024]; // X / A1 / A2 per node
    __shared__ float WoutL[2][16][128];               // MLP output, f32
    __shared__ float hF[2][16][128];                  // h0|h1 rows, f32
    __shared__ float4 yF[2][16];
    __shared__ int   eLi[2][16];
    __shared__ int   srcLi[2][16];
    __shared__ float sVs[2][256];
    __shared__ float gLs[2][32];
    short* const WB = (short*)WB4;

    const int t = threadIdx.x;
    const int half = t >> 8;
    const int j = t & 255;
    const int n0 = blockIdx.x * 2;
    const int n = n0 + half;
    const int d0 = cnt[n0];
    const int d1 = cnt[n0 + 1];
    const int deg = half ? d1 : d0;
    const int start = rowstart[n];
    const int chunks = ((d0 > d1 ? d0 : d1) + 15) >> 4;

    // stage shared weights
    {
        const uint4* wsrc = (const uint4*)wblob;
        #pragma unroll
        for (int i = 0; i < 4; ++i) WB4[t + i * 512] = wsrc[t + i * 512];
    }

    const int lane = t & 63;
    const int q = lane >> 4;
    const int c = lane & 15;
    const int sw = c & 7;
    const int wv = (t >> 6) & 3;    // wave-in-node
    const f32x4 zf = {0.f, 0.f, 0.f, 0.f};

    // per-thread TP component mapping
    int cls, u = 0, m = 0;
    if (j < 32)        { cls = 0; u = j; }
    else if (j < 64)   { cls = 1; u = j - 32; }
    else if (j < 160)  { cls = 2; const int i = j - 64;  u = i / 3; m = i - 3 * u; }
    else               { cls = 3; const int i = j - 160; u = i / 3; m = i - 3 * u; }
    const int comp = (cls == 0) ? u : (cls == 1) ? (96 + u) : (cls == 2) ? (32 + u) : (64 + u);

    short* const Xb  = &XA[half][0][0];
    short* const A1b = &XA[half][1][0];
    short* const A2b = &XA[half][2][0];

    float acc = 0.0f;
    for (int ch = 0; ch < chunks; ++ch) {
        const int base = ch * 16;
        const int nk = deg - base < 16 ? deg - base : 16;  // may be <= 0
        const int nkc = nk < 0 ? 0 : nk;
        __syncthreads();   // previous chunk's TP readers done
        if (j < nkc) {
            const int pp = start + base + j;
            const int e = eid[pp];
            eLi[half][j] = e;
            yF[half][j] = *(const float4*)(esh + (size_t)e * 4);
            srcLi[half][j] = esrc[e];
            // stage X row j (bf16, swizzled; logical kb0 = data, kb1..3 = zero)
            const float4 q0 = *(const float4*)(eemb + (size_t)e * 8);
            const float4 q1 = *(const float4*)(eemb + (size_t)e * 8 + 4);
            uint4 xv;
            xv.x = bf16rne(q0.x) | (bf16rne(q0.y) << 16);
            xv.y = bf16rne(q0.z) | (bf16rne(q0.w) << 16);
            xv.z = bf16rne(q1.x) | (bf16rne(q1.y) << 16);
            xv.w = bf16rne(q1.z) | (bf16rne(q1.w) << 16);
            uint4* Xr = (uint4*)&Xb[j * 64];
            const uint4 zz = {0u, 0u, 0u, 0u};
            const int myslot = j & 7;
            #pragma unroll
            for (int s = 0; s < 8; ++s) Xr[s] = (s == myslot) ? xv : zz;
        }
        __syncthreads();   // X / src / y ready

        // ---- h gather staging (float4 writes, 0-conflict pattern), 2 passes ----
        #pragma unroll
        for (int pass = 0; pass < 2; ++pass) {
            const int idx = pass * 256 + j;
            const int k = idx >> 5;          // edge 0..15
            const int c4 = (idx & 31) * 4;   // comp 0..124
            if (k < nkc) {
                const int src = srcLi[half][k];
                const ushort4 hv = (c4 < 32)
                    ? *(const ushort4*)(h0b + (size_t)src * 32 + c4)
                    : *(const ushort4*)(h1b + (size_t)src * 96 + (c4 - 32));
                float4 f;
                f.x = bf2f(hv.x); f.y = bf2f(hv.y); f.z = bf2f(hv.z); f.w = bf2f(hv.w);
                *(float4*)&hF[half][k][c4] = f;
            }
        }

        // ---- MLP layer 1: A1 = silu(X @ W0 / sqrt(8)), M=16 N=64(K=32) ----
        {
            const short8 af = *(const short8*)&Xb[c * 64 + ((q ^ sw) * 8)];
            const short8 bf = *(const short8*)&WB[(wv * 16 + c) * 64 + ((q ^ sw) * 8)];
            f32x4 a1 = __builtin_amdgcn_mfma_f32_16x16x32_bf16(af, bf, zf, 0, 0, 0);
            const float inv_s8 = 0.35355339059327373f;
            #pragma unroll
            for (int r = 0; r < 4; ++r) {
                const int mm = q * 4 + r;
                const int nn = wv * 16 + c;
                const float x = silu_f(a1[r] * inv_s8);
                A1b[mm * 64 + (((nn >> 3) ^ (mm & 7)) * 8) + (nn & 7)] = (short)bf16rne(x);
            }
        }
        __syncthreads();   // A1 ready

        // ---- MLP layer 2: A2 = silu(A1 @ W1 / 8), K=64 ----
        {
            f32x4 a2 = zf;
            #pragma unroll
            for (int kt = 0; kt < 2; ++kt) {
                const short8 af = *(const short8*)&A1b[c * 64 + (((kt * 4 + q) ^ sw) * 8)];
                const short8 bf = *(const short8*)&WB[4096 + (wv * 16 + c) * 64 + (((kt * 4 + q) ^ sw) * 8)];
                a2 = __builtin_amdgcn_mfma_f32_16x16x32_bf16(af, bf, a2, 0, 0, 0);
            }
            #pragma unroll
            for (int r = 0; r < 4; ++r) {
                const int mm = q * 4 + r;
                const int nn = wv * 16 + c;
                const float x = silu_f(a2[r] * 0.125f);
                A2b[mm * 64 + (((nn >> 3) ^ (mm & 7)) * 8) + (nn & 7)] = (short)bf16rne(x);
            }
        }
        __syncthreads();   // A2 ready

        // ---- MLP layer 3: Wout = A2 @ W2 / 8, N=128 ----
        #pragma unroll
        for (int h2 = 0; h2 < 2; ++h2) {
            const int nt = wv + h2 * 4;
            f32x4 a3 = zf;
            #pragma unroll
            for (int kt = 0; kt < 2; ++kt) {
                const short8 af = *(const short8*)&A2b[c * 64 + (((kt * 4 + q) ^ sw) * 8)];
                const short8 bf = *(const short8*)&WB[8192 + (nt * 16 + c) * 64 + (((kt * 4 + q) ^ sw) * 8)];
                a3 = __builtin_amdgcn_mfma_f32_16x16x32_bf16(af, bf, a3, 0, 0, 0);
            }
            #pragma unroll
            for (int r = 0; r < 4; ++r)
                WoutL[half][q * 4 + r][nt * 16 + c] = a3[r] * 0.125f;
        }
        __syncthreads();   // Wout + hF ready

        // ---- tensor product accumulate ----
        if (cls == 0) {
            for (int k = 0; k < nk; ++k)
                acc += WoutL[half][k][comp] * hF[half][k][u] * yF[half][k].x;
        } else if (cls == 1) {
            for (int k = 0; k < nk; ++k) {
                const float4 y = yF[half][k];
                const float d = hF[half][k][32 + u*3 + 0] * y.y
                              + hF[half][k][32 + u*3 + 1] * y.z
                              + hF[half][k][32 + u*3 + 2] * y.w;
                acc += WoutL[half][k][comp] * d;
            }
        } else if (cls == 2) {
            for (int k = 0; k < nk; ++k) {
                const float4 y = yF[half][k];
                const float ym = (m == 0) ? y.y : (m == 1) ? y.z : y.w;
                acc += WoutL[half][k][comp] * hF[half][k][u] * ym;
            }
        } else {
            for (int k = 0; k < nk; ++k)
                acc += WoutL[half][k][comp] * yF[half][k].x * hF[half][k][32 + u*3 + m];
        }
    }
    __syncthreads();
    const float cs  = 0.0625f;                 // 1/N_NEIGH
    const float cs3 = 0.03608439182435161f;    // cs / sqrt(3)
    sVs[half][j] = acc * ((cls == 1) ? cs3 : cs);
    __syncthreads();

    // ---- lin2 + gates + output ----
    const float l2 = 0.125f; // 1/sqrt(64)
    const float* sV = sVs[half];
    if (j < 32) {
        float a = 0.0f;
        #pragma unroll
        for (int k = 0; k < 64; ++k) a += sV[k] * l2w0[k * 64 + 32 + j];
        gLs[half][j] = silu_f(a * l2 + scg[n * 32 + j]);
    }
    __syncthreads();
    if (j < 32) {
        float a = 0.0f;
        #pragma unroll
        for (int k = 0; k < 64; ++k) a += sV[k] * l2w0[k * 64 + j];
        out[n * 128 + j] = silu_f(a * l2 + scs[n * 32 + j]);
    } else if (j < 128) {
        const int i = j - 32;
        const int v = i / 3;
        const int mm = i - 3 * v;
        float a = 0.0f;
        #pragma unroll
        for (int uu = 0; uu < 64; ++uu) a += sV[64 + uu * 3 + mm] * l2w1[uu * 32 + v];
        out[n * 128 + 32 + i] = gLs[half][v] * (a * l2 + scv[n * 96 + i]);
    }
}

extern "C" void kernel_launch(void* const* d_in, const int* in_sizes, int n_in,
                              void* d_out, int out_size, void* d_ws, size_t ws_size,
                              hipStream_t stream) {
    const float* nf   = (const float*)d_in[0];
    const float* za   = (const float*)d_in[1];
    const float* esh  = (const float*)d_in[2];
    const float* eemb = (const float*)d_in[3];
    const float* l1w0 = (const float*)d_in[4];
    const float* l1w1 = (const float*)d_in[5];
    const float* fw0  = (const float*)d_in[6];
    const float* fw1  = (const float*)d_in[7];
    const float* fw2  = (const float*)d_in[8];
    const float* wS   = (const float*)d_in[9];
    const float* wG   = (const float*)d_in[10];
    const float* wV   = (const float*)d_in[11];
    const float* l2w0 = (const float*)d_in[12];
    const float* l2w1 = (const float*)d_in[13];
    const int* esrc   = (const int*)d_in[14];
    const int* edst   = (const int*)d_in[15];
    float* out = (float*)d_out;

    // Workspace: ~41 MB
    float* ws  = (float*)d_ws;
    float* scs = ws;                         // 1,600,000 f32
    float* scg = scs + 1600000;              // 1,600,000 f32
    float* scv = scg + 1600000;              // 4,800,000 f32
    unsigned short* h0b = (unsigned short*)(scv + 4800000); // 1,600,000 bf16
    unsigned short* h1b = h0b + 1600000;     // 4,800,000 bf16
    int*   cnt      = (int*)(h1b + 4800000); // 50176
    int*   rowstart = cnt + 50176;           // 50176
    int*   cur      = rowstart + 50176;      // 50176
    int*   bsum     = cur + 50176;           // 256
    int*   boff     = bsum + 256;            // 256
    int*   eid      = boff + 256;            // 800,000
    unsigned short* wblob = (unsigned short*)(eid + 800000); // 16384 bf16 (32 KB)

    hipMemsetAsync(cnt, 0, 50176 * sizeof(int), stream);
    node_prep_kernel<<<NNODES, 128, 0, stream>>>(nf, l1w0, l1w1, h0b, h1b);
    sc_scalar_kernel<<<391, 256, 0, stream>>>(nf, za, wS, wG, scs, scg);
    sc_vec_kernel<<<586, 256, 0, stream>>>(nf, za, wV, scv);
    wprep_kernel<<<1, 256, 0, stream>>>(fw0, fw1, fw2, wblob);
    hist_kernel<<<3125, 256, 0, stream>>>(edst, cnt);
    scan_a_kernel<<<NCHUNK, 256, 0, stream>>>(cnt, bsum);
    scan_b_kernel<<<1, 256, 0, stream>>>(bsum, boff);
    scan_c_kernel<<<NCHUNK, 256, 0, stream>>>(cnt, boff, rowstart, cur);
    fill_kernel<<<3125, 256, 0, stream>>>(edst, cur, eid);
    fused_gather_kernel<<<NNODES / 2, 512, 0, stream>>>(
        eemb, esh, esrc, eid, rowstart, cnt, wblob, h0b, h1b,
        scs, scg, scv, l2w0, l2w1, out);
}